// Round 16
// baseline (290.508 us; speedup 1.0000x reference)
//
#include <hip/hip_runtime.h>

// SpikingNeuronLayer fused producer/consumer, R16 (= R15 + ALL-quarter
// tickets): finest scheduling granularity, minimal round quantization.
//   grid = 256 blocks x 512 threads -> 1 block/CU.
//   blocks 0..31   : scan role, wave 0 only (R7/R8 batch double-buffered
//                    register groups -- unchanged from R15).
//   blocks 32..255 : GEMM workers, R8's pipelined k-loop, 128x128 quarter
//                    tiles ONLY: 1024 tickets ch-major (ch = g>>7), so
//                    chunk cadence is ~linear and 224 workers stay desynced.
//   Signaling: block-level RELEASE after __syncthreads (proven R3-R15).
//   Scan chunk threshold: 4 quarter signals per (b,ch) (R13/R15-proven).
// xlin lands in d_out's spike region and is overwritten in place by the scan.

#define ALPHA_F 0.95122942450071402f  // float(exp(-1/20))

constexpr int Bb = 32, T = 1024, D = 512, Hh = 512;
constexpr int M = Bb * T;              // 32768
constexpr int NSCAN = 32;
constexpr int NBLOCKS = 256;           // 32 scan + 224 GEMM workers
constexpr int NT_ALL = 1024;           // 8 ch x 32 b x 4 col quarter tiles
constexpr int SIG_PER_CHUNK = 4;

#define BM 128
#define BN 256
#define BK 16
#define LDA (BM + 4)                   // 132
#define LDB (BN + 4)                   // 260

// ------------------------------------------------------------ DPP reduce ----
template <int CTRL>
__device__ __forceinline__ float dpp_add(float v) {
  int s = __builtin_amdgcn_update_dpp(0, __builtin_bit_cast(int, v),
                                      CTRL, 0xF, 0xF, true);
  return v + __builtin_bit_cast(float, s);
}

// 64-lane sum; result valid in lane 63 only (caller readlanes).
__device__ __forceinline__ float dpp_reduce(float v) {
  v = dpp_add<0x111>(v);  // row_shr:1
  v = dpp_add<0x112>(v);  // row_shr:2
  v = dpp_add<0x114>(v);  // row_shr:4
  v = dpp_add<0x118>(v);  // row_shr:8
  v = dpp_add<0x142>(v);  // row_bcast15
  v = dpp_add<0x143>(v);  // row_bcast31 -> lane 63 = total
  return v;
}

// ------------------------------------------------------------- zero ws ----
__global__ void zero_ws_kernel(unsigned* ws) {
  if (threadIdx.x < 257) ws[threadIdx.x] = 0;  // prog[256] + ticket
}

// --------------------------------------------------- pipelined tile body ----
// CF = column fragments: 1 -> 128x128 tile. (Path validated R12/R15:
// passed, absmax 0.) Per-output-element fmaf k-chain identical to all
// previous rounds.
template <int CF>
__device__ __forceinline__ void gemm_tile(
    const float* __restrict__ X, const float* __restrict__ W,
    const float* __restrict__ bias, float* out,
    int rowA, int rowB, int tid,
    float (&As)[2][BK][LDA], float (&Bs)[2][BK][LDB]) {
  const int tm = tid >> 5;   // 0..15
  const int tn = tid & 31;   // 0..31
  const int sr = tid >> 2;          // staging row 0..127
  const int sc4 = (tid & 3) << 2;   // staging col 0,4,8,12

  float4 ra, rb0, rb1;  // staged slab (registers)

  float acc[8][4 * CF];
#pragma unroll
  for (int i = 0; i < 8; ++i)
#pragma unroll
    for (int j = 0; j < 4 * CF; ++j) acc[i][j] = 0.f;

#define GLOADT(k0)                                                           \
  {                                                                          \
    ra  = *(const float4*)(X + (size_t)(rowA + sr) * D + (k0) + sc4);        \
    rb0 = *(const float4*)(W + (size_t)(rowB + sr) * D + (k0) + sc4);        \
    if (CF == 2)                                                             \
      rb1 = *(const float4*)(W + (size_t)(rowB + 128 + sr) * D + (k0) + sc4);\
  }

#define SWRITET(bf)                                                          \
  {                                                                          \
    As[bf][sc4 + 0][sr] = ra.x; As[bf][sc4 + 1][sr] = ra.y;                  \
    As[bf][sc4 + 2][sr] = ra.z; As[bf][sc4 + 3][sr] = ra.w;                  \
    Bs[bf][sc4 + 0][sr] = rb0.x; Bs[bf][sc4 + 1][sr] = rb0.y;                \
    Bs[bf][sc4 + 2][sr] = rb0.z; Bs[bf][sc4 + 3][sr] = rb0.w;                \
    if (CF == 2) {                                                           \
      Bs[bf][sc4 + 0][sr + 128] = rb1.x; Bs[bf][sc4 + 1][sr + 128] = rb1.y;  \
      Bs[bf][sc4 + 2][sr + 128] = rb1.z; Bs[bf][sc4 + 3][sr + 128] = rb1.w;  \
    }                                                                        \
  }

  GLOADT(0)
  int cur = 0;
  for (int k0 = 0; k0 < D; k0 += BK) {
    SWRITET(cur)       // compiler inserts vmcnt wait before first write
    __syncthreads();   // buf[cur] ready for all
    if (k0 + BK < D) GLOADT(k0 + BK)  // in flight during compute below
#pragma unroll
    for (int k = 0; k < BK; ++k) {
      float4 a0 = *(const float4*)&As[cur][k][tm * 4];
      float4 a1 = *(const float4*)&As[cur][k][64 + tm * 4];
      float4 b0 = *(const float4*)&Bs[cur][k][tn * 4];
      float av[8] = {a0.x, a0.y, a0.z, a0.w, a1.x, a1.y, a1.z, a1.w};
      if (CF == 2) {
        float4 b1 = *(const float4*)&Bs[cur][k][128 + tn * 4];
        float bv[8] = {b0.x, b0.y, b0.z, b0.w, b1.x, b1.y, b1.z, b1.w};
#pragma unroll
        for (int i = 0; i < 8; ++i)
#pragma unroll
          for (int j = 0; j < 8; ++j)
            acc[i][j % (4 * CF)] = (CF == 2)
                ? fmaf(av[i], bv[j], acc[i][j % (4 * CF)])
                : acc[i][j % (4 * CF)];
      } else {
        float bv[4] = {b0.x, b0.y, b0.z, b0.w};
#pragma unroll
        for (int i = 0; i < 8; ++i)
#pragma unroll
          for (int j = 0; j < 4; ++j)
            acc[i][j] = fmaf(av[i], bv[j], acc[i][j]);
      }
    }
    cur ^= 1;
    // one barrier per iter: buf overwritten next iter was last read at
    // iter-2, and all waves passed this iter's barrier after that -> WAR ok.
  }

  const int c0 = rowB + tn * 4;
  float4 bb0 = *(const float4*)(bias + c0);
  float4 bb1;
  if (CF == 2) bb1 = *(const float4*)(bias + c0 + 128);
#pragma unroll
  for (int i = 0; i < 8; ++i) {
    const int r = rowA + ((i < 4) ? (tm * 4 + i) : (64 + tm * 4 + (i - 4)));
    float4 v0;
    v0.x = acc[i][0] + bb0.x; v0.y = acc[i][1] + bb0.y;
    v0.z = acc[i][2] + bb0.z; v0.w = acc[i][3] + bb0.w;
    *(float4*)(out + (size_t)r * Hh + c0) = v0;
    if (CF == 2) {
      float4 v1;
      v1.x = acc[i][4] + bb1.x; v1.y = acc[i][5] + bb1.y;
      v1.z = acc[i][6] + bb1.z; v1.w = acc[i][7] + bb1.w;
      *(float4*)(out + (size_t)r * Hh + c0 + 128) = v1;
    }
  }
#undef GLOADT
#undef SWRITET
}

// ------------------------------------------------------------ fused ----
__global__ __launch_bounds__(512) void fused_kernel(
    const float* __restrict__ X,     // [M, D]
    const float* __restrict__ W,     // [H, D]
    const float* __restrict__ bias,  // [H]
    const float* __restrict__ ta,    // [H]
    float* out,                      // [M, H]: xlin then spikes (in place)
    float* memout,                   // [B, H]
    unsigned* ws)                    // prog[256] (per mt), ticket
{
  unsigned* prog = ws;
  unsigned* ticket = ws + 256;
  const int tid = threadIdx.x;

  if (blockIdx.x >= NSCAN) {
    // -------------------- GEMM role (persistent, ticketed, pipelined) -----
    __shared__ float As[2][BK][LDA];   // 16.9 KB
    __shared__ float Bs[2][BK][LDB];   // 33.3 KB
    __shared__ unsigned s_g;

    for (;;) {
      __syncthreads();  // protects s_g WAR + LDS reuse across tiles
      if (tid == 0)
        s_g = __hip_atomic_fetch_add(ticket, 1u, __ATOMIC_RELAXED,
                                     __HIP_MEMORY_SCOPE_AGENT);
      __syncthreads();
      const unsigned g = s_g;
      if (g >= NT_ALL) break;  // uniform

      // all-quarter, ch-major: g = ch*128 + idx ; idx = b*4 + bn2 ;
      // mt = b*8 + ch ; col = bn2*128
      const int ch  = (int)(g >> 7);          // 0..7
      const int idx = (int)(g & 127u);
      const int b   = idx >> 2;               // 0..31
      const int bn2 = idx & 3;                // 0..3
      const int mt  = b * 8 + ch;             // 0..255
      gemm_tile<1>(X, W, bias, out, mt * BM, bn2 * 128, tid, As, Bs);

      __syncthreads();  // barrier drain: all waves' stores at vmcnt(0)
      if (tid == 0)
        __hip_atomic_fetch_add(prog + mt, 1u, __ATOMIC_RELEASE,
                               __HIP_MEMORY_SCOPE_AGENT);
    }
    return;
  }

  // ---------------------------------------------------------- scan role ----
  if (tid >= 64) return;  // one wave; rest of the block exits
  __builtin_amdgcn_s_setprio(3);

  const int b = blockIdx.x;
  const int lane = tid;
  float* base = out + (size_t)b * (size_t)(T * Hh);
  const int h0 = lane * 4;
  const int h1 = 256 + lane * 4;

  float4 tav0 = *(const float4*)(ta + h0);
  float4 tav1 = *(const float4*)(ta + h1);
  float tac[8] = {tav0.x, tav0.y, tav0.z, tav0.w,
                  tav1.x, tav1.y, tav1.z, tav1.w};

  // chunk (b,ch) ready when prog[b*8+ch] == 4 quarter signals
#define WAIT_CHUNK(idxc)                                                     \
  {                                                                          \
    unsigned* wp = prog + (idxc);                                            \
    while (__hip_atomic_load(wp, __ATOMIC_RELAXED,                           \
                             __HIP_MEMORY_SCOPE_AGENT) <                     \
           (unsigned)SIG_PER_CHUNK) {                                        \
      __builtin_amdgcn_s_sleep(2);                                           \
    }                                                                        \
    __builtin_amdgcn_fence(__ATOMIC_ACQUIRE, "agent");                       \
  }

  // Double-buffered 8-step register groups. All indices compile-time.
  float4 pA0[8], pB0[8], pA1[8], pB1[8];
  float cc[8], mr[8];
  bool fire[8];
#pragma unroll
  for (int i = 0; i < 8; ++i) fire[i] = false;

#define LOAD1(NA, NB, u, t)                                                  \
  NA[u] = *(const float4*)(base + (size_t)(t) * Hh + h0);                    \
  NB[u] = *(const float4*)(base + (size_t)(t) * Hh + h1);

#define STEPX(CA, CB, u, t, NXA, NXB, SPEC)                                  \
  {                                                                          \
    const float xu_[8] = {CA[u].x, CA[u].y, CA[u].z, CA[u].w,                \
                          CB[u].x, CB[u].y, CB[u].z, CB[u].w};               \
    _Pragma("unroll")                                                        \
    for (int i = 0; i < 8; ++i) mr[i] = fire[i] ? xu_[i] : cc[i];            \
    float s_ = ((mr[0] + mr[1]) + (mr[2] + mr[3])) +                         \
               ((mr[4] + mr[5]) + (mr[6] + mr[7]));                          \
    float q_ = ((fmaf(mr[0], mr[0], mr[1] * mr[1])) +                        \
                (fmaf(mr[2], mr[2], mr[3] * mr[3]))) +                       \
               ((fmaf(mr[4], mr[4], mr[5] * mr[5])) +                        \
                (fmaf(mr[6], mr[6], mr[7] * mr[7])));                        \
    if (SPEC) { /* speculative next-step update, overlaps reduce */          \
      const float4 nxa_ = (NXA), nxb_ = (NXB);                               \
      const float xn_[8] = {nxa_.x, nxa_.y, nxa_.z, nxa_.w,                  \
                            nxb_.x, nxb_.y, nxb_.z, nxb_.w};                 \
      _Pragma("unroll")                                                      \
      for (int i = 0; i < 8; ++i) cc[i] = fmaf(ALPHA_F, mr[i], xn_[i]);      \
    }                                                                        \
    s_ = dpp_reduce(s_);                                                     \
    q_ = dpp_reduce(q_);                                                     \
    float var_ = fmaf(s_ * s_, -(1.0f / Hh), q_) * (1.0f / (Hh - 1));        \
    var_ = fmaxf(var_, 0.f);                                                 \
    float sdl_ = __builtin_amdgcn_sqrtf(var_); /* lane 63 valid */           \
    const float sd_ = __builtin_bit_cast(                                    \
        float,                                                               \
        __builtin_amdgcn_readlane(__builtin_bit_cast(int, sdl_), 63));       \
    float sp_[8];                                                            \
    _Pragma("unroll")                                                        \
    for (int i = 0; i < 8; ++i) {                                            \
      fire[i] = mr[i] >= fmaf(0.1f, sd_, tac[i]);                            \
      sp_[i] = fire[i] ? 1.f : 0.f;                                          \
    }                                                                        \
    *(float4*)(base + (size_t)(t) * Hh + h0) =                               \
        make_float4(sp_[0], sp_[1], sp_[2], sp_[3]);                         \
    *(float4*)(base + (size_t)(t) * Hh + h1) =                               \
        make_float4(sp_[4], sp_[5], sp_[6], sp_[7]);                         \
  }

// One group: (optionally) issue next-group loads into NA/NB FIRST, then
// compute 8 steps from CA/CB. u=7's speculation reads NA[0]/NB[0] -- the
// load issued ~7 steps earlier in this same group (covered).
#define GROUP(CA, CB, NA, NB, T0, PF, LASTG)                                 \
  {                                                                          \
    if (PF) {                                                                \
      LOAD1(NA, NB, 0, (T0) + 8)  LOAD1(NA, NB, 1, (T0) + 9)                 \
      LOAD1(NA, NB, 2, (T0) + 10) LOAD1(NA, NB, 3, (T0) + 11)                \
      LOAD1(NA, NB, 4, (T0) + 12) LOAD1(NA, NB, 5, (T0) + 13)                \
      LOAD1(NA, NB, 6, (T0) + 14) LOAD1(NA, NB, 7, (T0) + 15)                \
    }                                                                        \
    STEPX(CA, CB, 0, (T0) + 0, CA[1], CB[1], 1)                              \
    STEPX(CA, CB, 1, (T0) + 1, CA[2], CB[2], 1)                              \
    STEPX(CA, CB, 2, (T0) + 2, CA[3], CB[3], 1)                              \
    STEPX(CA, CB, 3, (T0) + 3, CA[4], CB[4], 1)                              \
    STEPX(CA, CB, 4, (T0) + 4, CA[5], CB[5], 1)                              \
    STEPX(CA, CB, 5, (T0) + 5, CA[6], CB[6], 1)                              \
    STEPX(CA, CB, 6, (T0) + 6, CA[7], CB[7], 1)                              \
    STEPX(CA, CB, 7, (T0) + 7, NA[0], NB[0], !(LASTG))                       \
  }

  WAIT_CHUNK(b * 8);
  // prologue: buf0 <- steps 0..7
  LOAD1(pA0, pB0, 0, 0) LOAD1(pA0, pB0, 1, 1)
  LOAD1(pA0, pB0, 2, 2) LOAD1(pA0, pB0, 3, 3)
  LOAD1(pA0, pB0, 4, 4) LOAD1(pA0, pB0, 5, 5)
  LOAD1(pA0, pB0, 6, 6) LOAD1(pA0, pB0, 7, 7)
  // cc for t=0 is x_0 (mem starts at 0)
  cc[0] = pA0[0].x; cc[1] = pA0[0].y; cc[2] = pA0[0].z; cc[3] = pA0[0].w;
  cc[4] = pB0[0].x; cc[5] = pB0[0].y; cc[6] = pB0[0].z; cc[7] = pB0[0].w;

  for (int gp = 0; gp < 63; ++gp) {
    const int t0 = gp << 4;
    GROUP(pA0, pB0, pA1, pB1, t0, true, false)
    // GROUPB's prefetch (steps t0+16..t0+23) crosses a chunk boundary iff
    // (t0+16) % 128 == 0, i.e. gp % 8 == 7. Gate it. (uniform branch)
    if ((gp & 7) == 7) WAIT_CHUNK(b * 8 + ((t0 + 16) >> 7));
    GROUP(pA1, pB1, pA0, pB0, t0 + 8, true, false)
  }
  GROUP(pA0, pB0, pA1, pB1, 1008, true, false)
  GROUP(pA1, pB1, pA0, pB0, 1016, false, true)

#undef GROUP
#undef STEPX
#undef LOAD1
#undef WAIT_CHUNK

  float mf[8];
#pragma unroll
  for (int i = 0; i < 8; ++i) mf[i] = fire[i] ? 0.f : mr[i];
  *(float4*)(memout + (size_t)b * Hh + h0) = make_float4(mf[0], mf[1], mf[2], mf[3]);
  *(float4*)(memout + (size_t)b * Hh + h1) = make_float4(mf[4], mf[5], mf[6], mf[7]);
}

// ------------------------------------------------- fallback (two-kernel) ----
__global__ __launch_bounds__(256) void gemm_kernel(
    const float* __restrict__ X, const float* __restrict__ W,
    const float* __restrict__ bias, float* __restrict__ out) {
  const int bn = blockIdx.x, bm = blockIdx.y;
  __shared__ float As[BK][BM + 4];
  __shared__ float Bs[BK][BM + 4];
  const int tid = threadIdx.x, tm = tid >> 4, tn = tid & 15;
  float acc[8][8];
#pragma unroll
  for (int i = 0; i < 8; ++i)
#pragma unroll
    for (int j = 0; j < 8; ++j) acc[i][j] = 0.f;
  const int rowA = bm * BM, rowB = bn * BM;
  for (int k0 = 0; k0 < D; k0 += BK) {
    __syncthreads();
#pragma unroll
    for (int i = 0; i < 2; ++i) {
      const int f = tid * 2 + i, r = f >> 2, c4 = (f & 3) << 2;
      float4 a = *(const float4*)(X + (size_t)(rowA + r) * D + k0 + c4);
      As[c4 + 0][r] = a.x; As[c4 + 1][r] = a.y;
      As[c4 + 2][r] = a.z; As[c4 + 3][r] = a.w;
      float4 w = *(const float4*)(W + (size_t)(rowB + r) * D + k0 + c4);
      Bs[c4 + 0][r] = w.x; Bs[c4 + 1][r] = w.y;
      Bs[c4 + 2][r] = w.z; Bs[c4 + 3][r] = w.w;
    }
    __syncthreads();
#pragma unroll
    for (int k = 0; k < BK; ++k) {
      float4 a0 = *(const float4*)&As[k][tm * 4];
      float4 a1 = *(const float4*)&As[k][64 + tm * 4];
      float4 b0 = *(const float4*)&Bs[k][tn * 4];
      float4 b1 = *(const float4*)&Bs[k][64 + tn * 4];
      float av[8] = {a0.x, a0.y, a0.z, a0.w, a1.x, a1.y, a1.z, a1.w};
      float bv[8] = {b0.x, b0.y, b0.z, b0.w, b1.x, b1.y, b1.z, b1.w};
#pragma unroll
      for (int i = 0; i < 8; ++i)
#pragma unroll
        for (int j = 0; j < 8; ++j)
          acc[i][j] = fmaf(av[i], bv[j], acc[i][j]);
    }
  }
  const int c0 = rowB + tn * 4, c1 = rowB + 64 + tn * 4;
  float4 bb0 = *(const float4*)(bias + c0);
  float4 bb1 = *(const float4*)(bias + c1);
  float bc[8] = {bb0.x, bb0.y, bb0.z, bb0.w, bb1.x, bb1.y, bb1.z, bb1.w};
#pragma unroll
  for (int i = 0; i < 8; ++i) {
    const int r = rowA + ((i < 4) ? (tm * 4 + i) : (64 + tm * 4 + (i - 4)));
    float4 v0, v1;
    v0.x = acc[i][0] + bc[0]; v0.y = acc[i][1] + bc[1];
    v0.z = acc[i][2] + bc[2]; v0.w = acc[i][3] + bc[3];
    v1.x = acc[i][4] + bc[4]; v1.y = acc[i][5] + bc[5];
    v1.z = acc[i][6] + bc[6]; v1.w = acc[i][7] + bc[7];
    *(float4*)(out + (size_t)r * Hh + c0) = v0;
    *(float4*)(out + (size_t)r * Hh + c1) = v1;
  }
}

__global__ __launch_bounds__(64) void scan_kernel(
    float* __restrict__ xs, const float* __restrict__ ta,
    float* __restrict__ memout) {
  const int b = blockIdx.x, lane = threadIdx.x;
  float* base = xs + (size_t)b * (size_t)(T * Hh);
  const int h0 = lane * 4, h1 = 256 + lane * 4;
  float4 tav0 = *(const float4*)(ta + h0);
  float4 tav1 = *(const float4*)(ta + h1);
  float tac[8] = {tav0.x, tav0.y, tav0.z, tav0.w,
                  tav1.x, tav1.y, tav1.z, tav1.w};
  float4 pa[4], pb[4];
#pragma unroll
  for (int u = 0; u < 4; ++u) {
    pa[u] = *(const float4*)(base + (size_t)u * Hh + h0);
    pb[u] = *(const float4*)(base + (size_t)u * Hh + h1);
  }
  float xc[8], cc[8], mr[8];
  bool fire[8];
  {
    const float4 a = pa[0], bq = pb[0];
    xc[0] = a.x; xc[1] = a.y; xc[2] = a.z; xc[3] = a.w;
    xc[4] = bq.x; xc[5] = bq.y; xc[6] = bq.z; xc[7] = bq.w;
  }
#pragma unroll
  for (int i = 0; i < 8; ++i) { cc[i] = xc[i]; fire[i] = false; }
#pragma unroll 4
  for (int t = 0; t < T; ++t) {
    const int u = t & 3;
    if (t + 4 < T) {
      pa[u] = *(const float4*)(base + (size_t)(t + 4) * Hh + h0);
      pb[u] = *(const float4*)(base + (size_t)(t + 4) * Hh + h1);
    }
#pragma unroll
    for (int i = 0; i < 8; ++i) mr[i] = fire[i] ? xc[i] : cc[i];
    float s = ((mr[0] + mr[1]) + (mr[2] + mr[3])) +
              ((mr[4] + mr[5]) + (mr[6] + mr[7]));
    float q = ((mr[0] * mr[0] + mr[1] * mr[1]) +
               (mr[2] * mr[2] + mr[3] * mr[3])) +
              ((mr[4] * mr[4] + mr[5] * mr[5]) +
               (mr[6] * mr[6] + mr[7] * mr[7]));
    {
      const float4 na = pa[(u + 1) & 3];
      const float4 nb = pb[(u + 1) & 3];
      xc[0] = na.x; xc[1] = na.y; xc[2] = na.z; xc[3] = na.w;
      xc[4] = nb.x; xc[5] = nb.y; xc[6] = nb.z; xc[7] = nb.w;
#pragma unroll
      for (int i = 0; i < 8; ++i) cc[i] = fmaf(ALPHA_F, mr[i], xc[i]);
    }
    s = dpp_reduce(s);
    q = dpp_reduce(q);
    float var = fmaxf((q - s * s * (1.0f / Hh)) * (1.0f / (Hh - 1)), 0.f);
    float sdl = __builtin_amdgcn_sqrtf(var);
    const float sd = __builtin_bit_cast(
        float, __builtin_amdgcn_readlane(__builtin_bit_cast(int, sdl), 63));
    float sp[8];
#pragma unroll
    for (int i = 0; i < 8; ++i) {
      fire[i] = mr[i] >= fmaf(0.1f, sd, tac[i]);
      sp[i] = fire[i] ? 1.f : 0.f;
    }
    *(float4*)(base + (size_t)t * Hh + h0) = make_float4(sp[0], sp[1], sp[2], sp[3]);
    *(float4*)(base + (size_t)t * Hh + h1) = make_float4(sp[4], sp[5], sp[6], sp[7]);
  }
  float mf[8];
#pragma unroll
  for (int i = 0; i < 8; ++i) mf[i] = fire[i] ? 0.f : mr[i];
  *(float4*)(memout + (size_t)b * Hh + h0) = make_float4(mf[0], mf[1], mf[2], mf[3]);
  *(float4*)(memout + (size_t)b * Hh + h1) = make_float4(mf[4], mf[5], mf[6], mf[7]);
}

// -------------------------------------------------------------- launch ----
extern "C" void kernel_launch(void* const* d_in, const int* in_sizes, int n_in,
                              void* d_out, int out_size, void* d_ws,
                              size_t ws_size, hipStream_t stream) {
  const float* x    = (const float*)d_in[0];
  const float* W    = (const float*)d_in[1];
  const float* bias = (const float*)d_in[2];
  const float* ta   = (const float*)d_in[3];

  float* out    = (float*)d_out;
  float* spikes = out;
  float* memout = out + (size_t)Bb * T * Hh;

  if (ws_size >= 257 * sizeof(unsigned)) {
    unsigned* ws = (unsigned*)d_ws;
    zero_ws_kernel<<<dim3(1), dim3(512), 0, stream>>>(ws);
    fused_kernel<<<dim3(NBLOCKS), dim3(512), 0, stream>>>(
        x, W, bias, ta, spikes, memout, ws);
  } else {
    dim3 ggrid(Hh / 128, M / BM);
    gemm_kernel<<<ggrid, dim3(256), 0, stream>>>(x, W, bias, spikes);
    scan_kernel<<<dim3(Bb), dim3(64), 0, stream>>>(spikes, ta, memout);
  }
}

// Round 17
// 284.517 us; speedup vs baseline: 1.0211x; 1.0211x over previous
//
#include <hip/hip_runtime.h>

// SpikingNeuronLayer fused producer/consumer, R17 (= R15 + tail-quarters):
//   grid = 256 blocks x 512 threads -> 1 block/CU.
//   blocks 0..31   : scan role, wave 0 only (R7/R8 batch double-buffered
//                    register groups -- unchanged).
//   blocks 32..255 : GEMM workers, R8's pipelined k-loop. Ticket space:
//                    [0,128)   = ch0 QUARTER tiles  (scan starts ~60us)
//                    [128,512) = ch1..6 FULL 128x256 tiles (efficient bulk)
//                    [512,640) = ch7 QUARTER tiles  (kills the 2.0-round
//                                synchronization quantum of 448 fulls)
//   Signaling: block-level RELEASE after __syncthreads (proven R3-R16).
//   Scan thresholds: ch0/ch7 -> 4 quarter signals, ch1..6 -> 2 full signals.
// xlin lands in d_out's spike region and is overwritten in place by the scan.

#define ALPHA_F 0.95122942450071402f  // float(exp(-1/20))

constexpr int Bb = 32, T = 1024, D = 512, Hh = 512;
constexpr int M = Bb * T;              // 32768
constexpr int NSCAN = 32;
constexpr int NBLOCKS = 256;           // 32 scan + 224 GEMM workers
constexpr int NT_Q0  = 128;            // ch0 quarters
constexpr int NT_F   = 512;            // + 384 fulls (ch1..6) -> [128,512)
constexpr int NT_ALL = 640;            // + 128 ch7 quarters  -> [512,640)

#define BM 128
#define BN 256
#define BK 16
#define LDA (BM + 4)                   // 132
#define LDB (BN + 4)                   // 260

// ------------------------------------------------------------ DPP reduce ----
template <int CTRL>
__device__ __forceinline__ float dpp_add(float v) {
  int s = __builtin_amdgcn_update_dpp(0, __builtin_bit_cast(int, v),
                                      CTRL, 0xF, 0xF, true);
  return v + __builtin_bit_cast(float, s);
}

// 64-lane sum; result valid in lane 63 only (caller readlanes).
__device__ __forceinline__ float dpp_reduce(float v) {
  v = dpp_add<0x111>(v);  // row_shr:1
  v = dpp_add<0x112>(v);  // row_shr:2
  v = dpp_add<0x114>(v);  // row_shr:4
  v = dpp_add<0x118>(v);  // row_shr:8
  v = dpp_add<0x142>(v);  // row_bcast15
  v = dpp_add<0x143>(v);  // row_bcast31 -> lane 63 = total
  return v;
}

// ------------------------------------------------------------- zero ws ----
__global__ void zero_ws_kernel(unsigned* ws) {
  if (threadIdx.x < 257) ws[threadIdx.x] = 0;  // prog[256] + ticket
}

// --------------------------------------------------- pipelined tile body ----
// CF = column fragments: 2 -> 128x256 tile, 1 -> 128x128. Both paths
// validated (R12/R15/R16: passed, absmax 0). Per-output-element fmaf
// k-chain identical in both.
template <int CF>
__device__ __forceinline__ void gemm_tile(
    const float* __restrict__ X, const float* __restrict__ W,
    const float* __restrict__ bias, float* out,
    int rowA, int rowB, int tid,
    float (&As)[2][BK][LDA], float (&Bs)[2][BK][LDB]) {
  const int tm = tid >> 5;   // 0..15
  const int tn = tid & 31;   // 0..31
  const int sr = tid >> 2;          // staging row 0..127
  const int sc4 = (tid & 3) << 2;   // staging col 0,4,8,12

  float4 ra, rb0, rb1;  // staged slab (registers)

  float acc[8][4 * CF];
#pragma unroll
  for (int i = 0; i < 8; ++i)
#pragma unroll
    for (int j = 0; j < 4 * CF; ++j) acc[i][j] = 0.f;

#define GLOADT(k0)                                                           \
  {                                                                          \
    ra  = *(const float4*)(X + (size_t)(rowA + sr) * D + (k0) + sc4);        \
    rb0 = *(const float4*)(W + (size_t)(rowB + sr) * D + (k0) + sc4);        \
    if (CF == 2)                                                             \
      rb1 = *(const float4*)(W + (size_t)(rowB + 128 + sr) * D + (k0) + sc4);\
  }

#define SWRITET(bf)                                                          \
  {                                                                          \
    As[bf][sc4 + 0][sr] = ra.x; As[bf][sc4 + 1][sr] = ra.y;                  \
    As[bf][sc4 + 2][sr] = ra.z; As[bf][sc4 + 3][sr] = ra.w;                  \
    Bs[bf][sc4 + 0][sr] = rb0.x; Bs[bf][sc4 + 1][sr] = rb0.y;                \
    Bs[bf][sc4 + 2][sr] = rb0.z; Bs[bf][sc4 + 3][sr] = rb0.w;                \
    if (CF == 2) {                                                           \
      Bs[bf][sc4 + 0][sr + 128] = rb1.x; Bs[bf][sc4 + 1][sr + 128] = rb1.y;  \
      Bs[bf][sc4 + 2][sr + 128] = rb1.z; Bs[bf][sc4 + 3][sr + 128] = rb1.w;  \
    }                                                                        \
  }

  GLOADT(0)
  int cur = 0;
  for (int k0 = 0; k0 < D; k0 += BK) {
    SWRITET(cur)       // compiler inserts vmcnt wait before first write
    __syncthreads();   // buf[cur] ready for all
    if (k0 + BK < D) GLOADT(k0 + BK)  // in flight during compute below
#pragma unroll
    for (int k = 0; k < BK; ++k) {
      float4 a0 = *(const float4*)&As[cur][k][tm * 4];
      float4 a1 = *(const float4*)&As[cur][k][64 + tm * 4];
      float4 b0 = *(const float4*)&Bs[cur][k][tn * 4];
      float av[8] = {a0.x, a0.y, a0.z, a0.w, a1.x, a1.y, a1.z, a1.w};
      if (CF == 2) {
        float4 b1 = *(const float4*)&Bs[cur][k][128 + tn * 4];
        float bv[8] = {b0.x, b0.y, b0.z, b0.w, b1.x, b1.y, b1.z, b1.w};
#pragma unroll
        for (int i = 0; i < 8; ++i)
#pragma unroll
          for (int j = 0; j < 8; ++j)
            acc[i][j % (4 * CF)] = (CF == 2)
                ? fmaf(av[i], bv[j], acc[i][j % (4 * CF)])
                : acc[i][j % (4 * CF)];
      } else {
        float bv[4] = {b0.x, b0.y, b0.z, b0.w};
#pragma unroll
        for (int i = 0; i < 8; ++i)
#pragma unroll
          for (int j = 0; j < 4; ++j)
            acc[i][j] = fmaf(av[i], bv[j], acc[i][j]);
      }
    }
    cur ^= 1;
    // one barrier per iter: buf overwritten next iter was last read at
    // iter-2, and all waves passed this iter's barrier after that -> WAR ok.
  }

  const int c0 = rowB + tn * 4;
  float4 bb0 = *(const float4*)(bias + c0);
  float4 bb1;
  if (CF == 2) bb1 = *(const float4*)(bias + c0 + 128);
#pragma unroll
  for (int i = 0; i < 8; ++i) {
    const int r = rowA + ((i < 4) ? (tm * 4 + i) : (64 + tm * 4 + (i - 4)));
    float4 v0;
    v0.x = acc[i][0] + bb0.x; v0.y = acc[i][1] + bb0.y;
    v0.z = acc[i][2] + bb0.z; v0.w = acc[i][3] + bb0.w;
    *(float4*)(out + (size_t)r * Hh + c0) = v0;
    if (CF == 2) {
      float4 v1;
      v1.x = acc[i][4] + bb1.x; v1.y = acc[i][5] + bb1.y;
      v1.z = acc[i][6] + bb1.z; v1.w = acc[i][7] + bb1.w;
      *(float4*)(out + (size_t)r * Hh + c0 + 128) = v1;
    }
  }
#undef GLOADT
#undef SWRITET
}

// ------------------------------------------------------------ fused ----
__global__ __launch_bounds__(512) void fused_kernel(
    const float* __restrict__ X,     // [M, D]
    const float* __restrict__ W,     // [H, D]
    const float* __restrict__ bias,  // [H]
    const float* __restrict__ ta,    // [H]
    float* out,                      // [M, H]: xlin then spikes (in place)
    float* memout,                   // [B, H]
    unsigned* ws)                    // prog[256] (per mt), ticket
{
  unsigned* prog = ws;
  unsigned* ticket = ws + 256;
  const int tid = threadIdx.x;

  if (blockIdx.x >= NSCAN) {
    // -------------------- GEMM role (persistent, ticketed, pipelined) -----
    __shared__ float As[2][BK][LDA];   // 16.9 KB
    __shared__ float Bs[2][BK][LDB];   // 33.3 KB
    __shared__ unsigned s_g;

    for (;;) {
      __syncthreads();  // protects s_g WAR + LDS reuse across tiles
      if (tid == 0)
        s_g = __hip_atomic_fetch_add(ticket, 1u, __ATOMIC_RELAXED,
                                     __HIP_MEMORY_SCOPE_AGENT);
      __syncthreads();
      const unsigned g = s_g;
      if (g >= NT_ALL) break;  // uniform

      int mt;
      if (g < NT_Q0) {
        // ch0 quarter tiles (priority): g = b*4 + bn2 ; mt = b*8
        const int b = (int)(g >> 2);
        const int bn2 = (int)(g & 3u);
        mt = b * 8;  // ch = 0
        gemm_tile<1>(X, W, bias, out, mt * BM, bn2 * 128, tid, As, Bs);
      } else if (g < NT_F) {
        // full tiles, ch 1..6, ch-major: t = g-128 ; ch = 1 + t/64 ;
        // idx = t%64 ; mt = (idx>>1)*8 + ch ; bn = idx&1
        const int t = (int)(g - NT_Q0);
        const int chg = 1 + (t >> 6);
        const int idx = t & 63;
        mt = (idx >> 1) * 8 + chg;
        const int bn = idx & 1;
        gemm_tile<2>(X, W, bias, out, mt * BM, bn * BN, tid, As, Bs);
      } else {
        // ch7 quarter tiles (tail, anti-quantization): t = g-512 ;
        // b = t>>2 ; bn2 = t&3 ; mt = b*8 + 7
        const int t = (int)(g - NT_F);
        const int b = t >> 2;
        const int bn2 = t & 3;
        mt = b * 8 + 7;
        gemm_tile<1>(X, W, bias, out, mt * BM, bn2 * 128, tid, As, Bs);
      }

      __syncthreads();  // barrier drain: all waves' stores at vmcnt(0)
      if (tid == 0)
        __hip_atomic_fetch_add(prog + mt, 1u, __ATOMIC_RELEASE,
                               __HIP_MEMORY_SCOPE_AGENT);
    }
    return;
  }

  // ---------------------------------------------------------- scan role ----
  if (tid >= 64) return;  // one wave; rest of the block exits
  __builtin_amdgcn_s_setprio(3);

  const int b = blockIdx.x;
  const int lane = tid;
  float* base = out + (size_t)b * (size_t)(T * Hh);
  const int h0 = lane * 4;
  const int h1 = 256 + lane * 4;

  float4 tav0 = *(const float4*)(ta + h0);
  float4 tav1 = *(const float4*)(ta + h1);
  float tac[8] = {tav0.x, tav0.y, tav0.z, tav0.w,
                  tav1.x, tav1.y, tav1.z, tav1.w};

  // chunk (b,ch) ready: ch0/ch7 -> 4 quarter signals; ch1..6 -> 2 fulls
#define WAIT_CHUNK(idxc)                                                     \
  {                                                                          \
    unsigned* wp = prog + (idxc);                                            \
    const int ch_ = (idxc) & 7;                                              \
    const unsigned thr_ = (ch_ == 0 || ch_ == 7) ? 4u : 2u;                  \
    while (__hip_atomic_load(wp, __ATOMIC_RELAXED,                           \
                             __HIP_MEMORY_SCOPE_AGENT) < thr_) {             \
      __builtin_amdgcn_s_sleep(2);                                           \
    }                                                                        \
    __builtin_amdgcn_fence(__ATOMIC_ACQUIRE, "agent");                       \
  }

  // Double-buffered 8-step register groups. All indices compile-time.
  float4 pA0[8], pB0[8], pA1[8], pB1[8];
  float cc[8], mr[8];
  bool fire[8];
#pragma unroll
  for (int i = 0; i < 8; ++i) fire[i] = false;

#define LOAD1(NA, NB, u, t)                                                  \
  NA[u] = *(const float4*)(base + (size_t)(t) * Hh + h0);                    \
  NB[u] = *(const float4*)(base + (size_t)(t) * Hh + h1);

#define STEPX(CA, CB, u, t, NXA, NXB, SPEC)                                  \
  {                                                                          \
    const float xu_[8] = {CA[u].x, CA[u].y, CA[u].z, CA[u].w,                \
                          CB[u].x, CB[u].y, CB[u].z, CB[u].w};               \
    _Pragma("unroll")                                                        \
    for (int i = 0; i < 8; ++i) mr[i] = fire[i] ? xu_[i] : cc[i];            \
    float s_ = ((mr[0] + mr[1]) + (mr[2] + mr[3])) +                         \
               ((mr[4] + mr[5]) + (mr[6] + mr[7]));                          \
    float q_ = ((fmaf(mr[0], mr[0], mr[1] * mr[1])) +                        \
                (fmaf(mr[2], mr[2], mr[3] * mr[3]))) +                       \
               ((fmaf(mr[4], mr[4], mr[5] * mr[5])) +                        \
                (fmaf(mr[6], mr[6], mr[7] * mr[7])));                        \
    if (SPEC) { /* speculative next-step update, overlaps reduce */          \
      const float4 nxa_ = (NXA), nxb_ = (NXB);                               \
      const float xn_[8] = {nxa_.x, nxa_.y, nxa_.z, nxa_.w,                  \
                            nxb_.x, nxb_.y, nxb_.z, nxb_.w};                 \
      _Pragma("unroll")                                                      \
      for (int i = 0; i < 8; ++i) cc[i] = fmaf(ALPHA_F, mr[i], xn_[i]);      \
    }                                                                        \
    s_ = dpp_reduce(s_);                                                     \
    q_ = dpp_reduce(q_);                                                     \
    float var_ = fmaf(s_ * s_, -(1.0f / Hh), q_) * (1.0f / (Hh - 1));        \
    var_ = fmaxf(var_, 0.f);                                                 \
    float sdl_ = __builtin_amdgcn_sqrtf(var_); /* lane 63 valid */           \
    const float sd_ = __builtin_bit_cast(                                    \
        float,                                                               \
        __builtin_amdgcn_readlane(__builtin_bit_cast(int, sdl_), 63));       \
    float sp_[8];                                                            \
    _Pragma("unroll")                                                        \
    for (int i = 0; i < 8; ++i) {                                            \
      fire[i] = mr[i] >= fmaf(0.1f, sd_, tac[i]);                            \
      sp_[i] = fire[i] ? 1.f : 0.f;                                          \
    }                                                                        \
    *(float4*)(base + (size_t)(t) * Hh + h0) =                               \
        make_float4(sp_[0], sp_[1], sp_[2], sp_[3]);                         \
    *(float4*)(base + (size_t)(t) * Hh + h1) =                               \
        make_float4(sp_[4], sp_[5], sp_[6], sp_[7]);                         \
  }

// One group: (optionally) issue next-group loads into NA/NB FIRST, then
// compute 8 steps from CA/CB. u=7's speculation reads NA[0]/NB[0] -- the
// load issued ~7 steps earlier in this same group (covered).
#define GROUP(CA, CB, NA, NB, T0, PF, LASTG)                                 \
  {                                                                          \
    if (PF) {                                                                \
      LOAD1(NA, NB, 0, (T0) + 8)  LOAD1(NA, NB, 1, (T0) + 9)                 \
      LOAD1(NA, NB, 2, (T0) + 10) LOAD1(NA, NB, 3, (T0) + 11)                \
      LOAD1(NA, NB, 4, (T0) + 12) LOAD1(NA, NB, 5, (T0) + 13)                \
      LOAD1(NA, NB, 6, (T0) + 14) LOAD1(NA, NB, 7, (T0) + 15)                \
    }                                                                        \
    STEPX(CA, CB, 0, (T0) + 0, CA[1], CB[1], 1)                              \
    STEPX(CA, CB, 1, (T0) + 1, CA[2], CB[2], 1)                              \
    STEPX(CA, CB, 2, (T0) + 2, CA[3], CB[3], 1)                              \
    STEPX(CA, CB, 3, (T0) + 3, CA[4], CB[4], 1)                              \
    STEPX(CA, CB, 4, (T0) + 4, CA[5], CB[5], 1)                              \
    STEPX(CA, CB, 5, (T0) + 5, CA[6], CB[6], 1)                              \
    STEPX(CA, CB, 6, (T0) + 6, CA[7], CB[7], 1)                              \
    STEPX(CA, CB, 7, (T0) + 7, NA[0], NB[0], !(LASTG))                       \
  }

  WAIT_CHUNK(b * 8);
  // prologue: buf0 <- steps 0..7
  LOAD1(pA0, pB0, 0, 0) LOAD1(pA0, pB0, 1, 1)
  LOAD1(pA0, pB0, 2, 2) LOAD1(pA0, pB0, 3, 3)
  LOAD1(pA0, pB0, 4, 4) LOAD1(pA0, pB0, 5, 5)
  LOAD1(pA0, pB0, 6, 6) LOAD1(pA0, pB0, 7, 7)
  // cc for t=0 is x_0 (mem starts at 0)
  cc[0] = pA0[0].x; cc[1] = pA0[0].y; cc[2] = pA0[0].z; cc[3] = pA0[0].w;
  cc[4] = pB0[0].x; cc[5] = pB0[0].y; cc[6] = pB0[0].z; cc[7] = pB0[0].w;

  for (int gp = 0; gp < 63; ++gp) {
    const int t0 = gp << 4;
    GROUP(pA0, pB0, pA1, pB1, t0, true, false)
    // GROUPB's prefetch (steps t0+16..t0+23) crosses a chunk boundary iff
    // (t0+16) % 128 == 0, i.e. gp % 8 == 7. Gate it. (uniform branch)
    if ((gp & 7) == 7) WAIT_CHUNK(b * 8 + ((t0 + 16) >> 7));
    GROUP(pA1, pB1, pA0, pB0, t0 + 8, true, false)
  }
  GROUP(pA0, pB0, pA1, pB1, 1008, true, false)
  GROUP(pA1, pB1, pA0, pB0, 1016, false, true)

#undef GROUP
#undef STEPX
#undef LOAD1
#undef WAIT_CHUNK

  float mf[8];
#pragma unroll
  for (int i = 0; i < 8; ++i) mf[i] = fire[i] ? 0.f : mr[i];
  *(float4*)(memout + (size_t)b * Hh + h0) = make_float4(mf[0], mf[1], mf[2], mf[3]);
  *(float4*)(memout + (size_t)b * Hh + h1) = make_float4(mf[4], mf[5], mf[6], mf[7]);
}

// ------------------------------------------------- fallback (two-kernel) ----
__global__ __launch_bounds__(256) void gemm_kernel(
    const float* __restrict__ X, const float* __restrict__ W,
    const float* __restrict__ bias, float* __restrict__ out) {
  const int bn = blockIdx.x, bm = blockIdx.y;
  __shared__ float As[BK][BM + 4];
  __shared__ float Bs[BK][BM + 4];
  const int tid = threadIdx.x, tm = tid >> 4, tn = tid & 15;
  float acc[8][8];
#pragma unroll
  for (int i = 0; i < 8; ++i)
#pragma unroll
    for (int j = 0; j < 8; ++j) acc[i][j] = 0.f;
  const int rowA = bm * BM, rowB = bn * BM;
  for (int k0 = 0; k0 < D; k0 += BK) {
    __syncthreads();
#pragma unroll
    for (int i = 0; i < 2; ++i) {
      const int f = tid * 2 + i, r = f >> 2, c4 = (f & 3) << 2;
      float4 a = *(const float4*)(X + (size_t)(rowA + r) * D + k0 + c4);
      As[c4 + 0][r] = a.x; As[c4 + 1][r] = a.y;
      As[c4 + 2][r] = a.z; As[c4 + 3][r] = a.w;
      float4 w = *(const float4*)(W + (size_t)(rowB + r) * D + k0 + c4);
      Bs[c4 + 0][r] = w.x; Bs[c4 + 1][r] = w.y;
      Bs[c4 + 2][r] = w.z; Bs[c4 + 3][r] = w.w;
    }
    __syncthreads();
#pragma unroll
    for (int k = 0; k < BK; ++k) {
      float4 a0 = *(const float4*)&As[k][tm * 4];
      float4 a1 = *(const float4*)&As[k][64 + tm * 4];
      float4 b0 = *(const float4*)&Bs[k][tn * 4];
      float4 b1 = *(const float4*)&Bs[k][64 + tn * 4];
      float av[8] = {a0.x, a0.y, a0.z, a0.w, a1.x, a1.y, a1.z, a1.w};
      float bv[8] = {b0.x, b0.y, b0.z, b0.w, b1.x, b1.y, b1.z, b1.w};
#pragma unroll
      for (int i = 0; i < 8; ++i)
#pragma unroll
        for (int j = 0; j < 8; ++j)
          acc[i][j] = fmaf(av[i], bv[j], acc[i][j]);
    }
  }
  const int c0 = rowB + tn * 4, c1 = rowB + 64 + tn * 4;
  float4 bb0 = *(const float4*)(bias + c0);
  float4 bb1 = *(const float4*)(bias + c1);
  float bc[8] = {bb0.x, bb0.y, bb0.z, bb0.w, bb1.x, bb1.y, bb1.z, bb1.w};
#pragma unroll
  for (int i = 0; i < 8; ++i) {
    const int r = rowA + ((i < 4) ? (tm * 4 + i) : (64 + tm * 4 + (i - 4)));
    float4 v0, v1;
    v0.x = acc[i][0] + bc[0]; v0.y = acc[i][1] + bc[1];
    v0.z = acc[i][2] + bc[2]; v0.w = acc[i][3] + bc[3];
    v1.x = acc[i][4] + bc[4]; v1.y = acc[i][5] + bc[5];
    v1.z = acc[i][6] + bc[6]; v1.w = acc[i][7] + bc[7];
    *(float4*)(out + (size_t)r * Hh + c0) = v0;
    *(float4*)(out + (size_t)r * Hh + c1) = v1;
  }
}

__global__ __launch_bounds__(64) void scan_kernel(
    float* __restrict__ xs, const float* __restrict__ ta,
    float* __restrict__ memout) {
  const int b = blockIdx.x, lane = threadIdx.x;
  float* base = xs + (size_t)b * (size_t)(T * Hh);
  const int h0 = lane * 4, h1 = 256 + lane * 4;
  float4 tav0 = *(const float4*)(ta + h0);
  float4 tav1 = *(const float4*)(ta + h1);
  float tac[8] = {tav0.x, tav0.y, tav0.z, tav0.w,
                  tav1.x, tav1.y, tav1.z, tav1.w};
  float4 pa[4], pb[4];
#pragma unroll
  for (int u = 0; u < 4; ++u) {
    pa[u] = *(const float4*)(base + (size_t)u * Hh + h0);
    pb[u] = *(const float4*)(base + (size_t)u * Hh + h1);
  }
  float xc[8], cc[8], mr[8];
  bool fire[8];
  {
    const float4 a = pa[0], bq = pb[0];
    xc[0] = a.x; xc[1] = a.y; xc[2] = a.z; xc[3] = a.w;
    xc[4] = bq.x; xc[5] = bq.y; xc[6] = bq.z; xc[7] = bq.w;
  }
#pragma unroll
  for (int i = 0; i < 8; ++i) { cc[i] = xc[i]; fire[i] = false; }
#pragma unroll 4
  for (int t = 0; t < T; ++t) {
    const int u = t & 3;
    if (t + 4 < T) {
      pa[u] = *(const float4*)(base + (size_t)(t + 4) * Hh + h0);
      pb[u] = *(const float4*)(base + (size_t)(t + 4) * Hh + h1);
    }
#pragma unroll
    for (int i = 0; i < 8; ++i) mr[i] = fire[i] ? xc[i] : cc[i];
    float s = ((mr[0] + mr[1]) + (mr[2] + mr[3])) +
              ((mr[4] + mr[5]) + (mr[6] + mr[7]));
    float q = ((mr[0] * mr[0] + mr[1] * mr[1]) +
               (mr[2] * mr[2] + mr[3] * mr[3])) +
              ((mr[4] * mr[4] + mr[5] * mr[5]) +
               (mr[6] * mr[6] + mr[7] * mr[7]));
    {
      const float4 na = pa[(u + 1) & 3];
      const float4 nb = pb[(u + 1) & 3];
      xc[0] = na.x; xc[1] = na.y; xc[2] = na.z; xc[3] = na.w;
      xc[4] = nb.x; xc[5] = nb.y; xc[6] = nb.z; xc[7] = nb.w;
#pragma unroll
      for (int i = 0; i < 8; ++i) cc[i] = fmaf(ALPHA_F, mr[i], xc[i]);
    }
    s = dpp_reduce(s);
    q = dpp_reduce(q);
    float var = fmaxf((q - s * s * (1.0f / Hh)) * (1.0f / (Hh - 1)), 0.f);
    float sdl = __builtin_amdgcn_sqrtf(var);
    const float sd = __builtin_bit_cast(
        float, __builtin_amdgcn_readlane(__builtin_bit_cast(int, sdl), 63));
    float sp[8];
#pragma unroll
    for (int i = 0; i < 8; ++i) {
      fire[i] = mr[i] >= fmaf(0.1f, sd, tac[i]);
      sp[i] = fire[i] ? 1.f : 0.f;
    }
    *(float4*)(base + (size_t)t * Hh + h0) = make_float4(sp[0], sp[1], sp[2], sp[3]);
    *(float4*)(base + (size_t)t * Hh + h1) = make_float4(sp[4], sp[5], sp[6], sp[7]);
  }
  float mf[8];
#pragma unroll
  for (int i = 0; i < 8; ++i) mf[i] = fire[i] ? 0.f : mr[i];
  *(float4*)(memout + (size_t)b * Hh + h0) = make_float4(mf[0], mf[1], mf[2], mf[3]);
  *(float4*)(memout + (size_t)b * Hh + h1) = make_float4(mf[4], mf[5], mf[6], mf[7]);
}

// -------------------------------------------------------------- launch ----
extern "C" void kernel_launch(void* const* d_in, const int* in_sizes, int n_in,
                              void* d_out, int out_size, void* d_ws,
                              size_t ws_size, hipStream_t stream) {
  const float* x    = (const float*)d_in[0];
  const float* W    = (const float*)d_in[1];
  const float* bias = (const float*)d_in[2];
  const float* ta   = (const float*)d_in[3];

  float* out    = (float*)d_out;
  float* spikes = out;
  float* memout = out + (size_t)Bb * T * Hh;

  if (ws_size >= 257 * sizeof(unsigned)) {
    unsigned* ws = (unsigned*)d_ws;
    zero_ws_kernel<<<dim3(1), dim3(512), 0, stream>>>(ws);
    fused_kernel<<<dim3(NBLOCKS), dim3(512), 0, stream>>>(
        x, W, bias, ta, spikes, memout, ws);
  } else {
    dim3 ggrid(Hh / 128, M / BM);
    gemm_kernel<<<ggrid, dim3(256), 0, stream>>>(x, W, bias, spikes);
    scan_kernel<<<dim3(Bb), dim3(64), 0, stream>>>(spikes, ta, memout);
  }
}